// Round 1
// baseline (1166.310 us; speedup 1.0000x reference)
//
#include <hip/hip_runtime.h>

#define LL 1024
#define DD 512
#define HH 8
#define EE 64
#define LDX (LL*DD)

typedef _Float16 h8 __attribute__((ext_vector_type(8)));
typedef float f4 __attribute__((ext_vector_type(4)));
typedef int i4 __attribute__((ext_vector_type(4)));

__device__ __forceinline__ f4 mfma16(h8 a, h8 b, f4 c) {
    return __builtin_amdgcn_mfma_f32_16x16x32_f16(a, b, c, 0, 0, 0);
}

// ---------------- K1: K/V all heads + Q head 0 ----------------
__global__ __launch_bounds__(256) void k_qkv0(
    const float* __restrict__ x, const float* __restrict__ Wq,
    const float* __restrict__ Wk, const float* __restrict__ Wv,
    _Float16* __restrict__ qw, _Float16* __restrict__ kw, _Float16* __restrict__ vw)
{
    const int l0 = blockIdx.x * 64;
    const int b  = blockIdx.y;
    const int z  = blockIdx.z;            // 0..7 K, 8..15 V, 16 Q(head0)
    const float* W; _Float16* out; int h; float mul = 1.f;
    if (z < 8)       { h = z;     W = Wk + (size_t)h*DD*EE; out = kw; }
    else if (z < 16) { h = z - 8; W = Wv + (size_t)h*DD*EE; out = vw; }
    else             { h = 0;     W = Wq;                   out = qw; mul = 0.125f; }
    out += ((size_t)(b*HH + h)*LL + l0) * EE;

    __shared__ _Float16 As[64][72];
    __shared__ _Float16 Bs[64][72];

    const int t = threadIdx.x;
    const int wv = t >> 6, lane = t & 63;
    const int m = lane & 15, qd = lane >> 4;
    const int lrow = t >> 2, lc0 = (t & 3) * 16;
    const float* xrow = x + (size_t)b*LDX + (size_t)(l0 + lrow)*DD;

    f4 acc[4] = {};

    for (int kk = 0; kk < DD; kk += 64) {
        // A tile: x rows -> f16 (coalesced float4 reads)
        #pragma unroll
        for (int i = 0; i < 16; i += 4) {
            f4 v4 = *(const f4*)(xrow + kk + lc0 + i);
            #pragma unroll
            for (int j = 0; j < 4; ++j) As[lrow][lc0 + i + j] = (_Float16)v4[j];
        }
        // B tile: W[d][e] -> Bs[e][d]  (transposed so b-frag reads are k-contiguous)
        {
            const int e = t & 63, dd0 = t >> 6;
            #pragma unroll
            for (int d = 0; d < 64; d += 4)
                Bs[e][d + dd0] = (_Float16)W[(size_t)(kk + d + dd0)*EE + e];
        }
        __syncthreads();
        #pragma unroll
        for (int ks = 0; ks < 64; ks += 32) {
            h8 a = *(const h8*)&As[16*wv + m][ks + 8*qd];
            #pragma unroll
            for (int nt = 0; nt < 4; ++nt) {
                h8 bb = *(const h8*)&Bs[16*nt + m][ks + 8*qd];
                acc[nt] = mfma16(a, bb, acc[nt]);
            }
        }
        __syncthreads();
    }
    #pragma unroll
    for (int nt = 0; nt < 4; ++nt)
        #pragma unroll
        for (int r = 0; r < 4; ++r) {
            int row = 16*wv + 4*qd + r;
            out[(size_t)row*EE + 16*nt + m] = (_Float16)(acc[nt][r] * mul);
        }
}

// ---------------- K2: Q heads 1..7, gather fused into A stage ----------------
__global__ __launch_bounds__(256) void k_qshuf(
    const float* __restrict__ x, const int* __restrict__ perms,
    const float* __restrict__ Wq, _Float16* __restrict__ qw)
{
    const int l0 = blockIdx.x * 64;
    const int b  = blockIdx.y;
    const int h  = blockIdx.z + 1;
    const float* W = Wq + (size_t)h*DD*EE;
    _Float16* out = qw + ((size_t)(b*HH + h)*LL + l0) * EE;
    const int* prow = perms + (size_t)(h-1)*LDX + (size_t)l0*DD;
    const float* xb = x + (size_t)b*LDX;

    __shared__ _Float16 As[64][72];
    __shared__ _Float16 Bs[64][72];

    const int t = threadIdx.x;
    const int wv = t >> 6, lane = t & 63;
    const int m = lane & 15, qd = lane >> 4;
    const int lrow = t >> 2, lc0 = (t & 3) * 16;

    f4 acc[4] = {};

    for (int kk = 0; kk < DD; kk += 64) {
        const int* ps = prow + (size_t)lrow*DD + kk + lc0;
        #pragma unroll
        for (int i = 0; i < 16; i += 4) {
            i4 p4 = *(const i4*)(ps + i);
            #pragma unroll
            for (int j = 0; j < 4; ++j) As[lrow][lc0 + i + j] = (_Float16)xb[p4[j]];
        }
        {
            const int e = t & 63, dd0 = t >> 6;
            #pragma unroll
            for (int d = 0; d < 64; d += 4)
                Bs[e][d + dd0] = (_Float16)W[(size_t)(kk + d + dd0)*EE + e];
        }
        __syncthreads();
        #pragma unroll
        for (int ks = 0; ks < 64; ks += 32) {
            h8 a = *(const h8*)&As[16*wv + m][ks + 8*qd];
            #pragma unroll
            for (int nt = 0; nt < 4; ++nt) {
                h8 bb = *(const h8*)&Bs[16*nt + m][ks + 8*qd];
                acc[nt] = mfma16(a, bb, acc[nt]);
            }
        }
        __syncthreads();
    }
    #pragma unroll
    for (int nt = 0; nt < 4; ++nt)
        #pragma unroll
        for (int r = 0; r < 4; ++r) {
            int row = 16*wv + 4*qd + r;
            out[(size_t)row*EE + 16*nt + m] = (_Float16)(acc[nt][r] * 0.125f);
        }
}

// ---------------- K3: attention (no-max streaming softmax) ----------------
__global__ __launch_bounds__(256) void k_attn(
    const _Float16* __restrict__ qw, const _Float16* __restrict__ kw,
    const _Float16* __restrict__ vw, _Float16* __restrict__ oa)
{
    const int l0 = blockIdx.x * 64;
    const int bh = blockIdx.y;
    const int b = bh >> 3, h = bh & 7;
    const _Float16* qb = qw + ((size_t)bh*LL + l0)*EE;
    const _Float16* kb = kw + (size_t)bh*LL*EE;
    const _Float16* vb = vw + (size_t)bh*LL*EE;

    __shared__ _Float16 Qs[64][72], Ks[64][72], Vts[64][72], Ps[64][72];
    __shared__ float lsum[4][64];
    __shared__ float lfin[64];

    const int t = threadIdx.x;
    const int wv = t >> 6, lane = t & 63;
    const int m = lane & 15, qd = lane >> 4;
    const int lrow = t >> 2, lc0 = (t & 3) * 16;

    {   // Q tile (already scaled by 1/8): A-layout [q][e]
        const _Float16* s = qb + (size_t)lrow*EE + lc0;
        *(h8*)&Qs[lrow][lc0]     = *(const h8*)s;
        *(h8*)&Qs[lrow][lc0 + 8] = *(const h8*)(s + 8);
    }

    f4 oacc[4] = {};
    float lrun = 0.f;

    for (int kt = 0; kt < 16; ++kt) {
        {   // K tile natural [key][e] (== B-layout [n][k]); V transposed [e][key]
            const _Float16* s = kb + (size_t)(kt*64 + lrow)*EE + lc0;
            *(h8*)&Ks[lrow][lc0]     = *(const h8*)s;
            *(h8*)&Ks[lrow][lc0 + 8] = *(const h8*)(s + 8);
            const _Float16* s2 = vb + (size_t)(kt*64 + lrow)*EE + lc0;
            h8 v0 = *(const h8*)s2;
            h8 v1 = *(const h8*)(s2 + 8);
            #pragma unroll
            for (int i = 0; i < 8; ++i) Vts[lc0 + i][lrow]     = v0[i];
            #pragma unroll
            for (int i = 0; i < 8; ++i) Vts[lc0 + 8 + i][lrow] = v1[i];
        }
        __syncthreads();

        // S = Q·K^T  (scale pre-folded into Q)
        f4 sacc[4] = {};
        #pragma unroll
        for (int ks = 0; ks < 64; ks += 32) {
            h8 a = *(const h8*)&Qs[16*wv + m][ks + 8*qd];
            #pragma unroll
            for (int nt = 0; nt < 4; ++nt) {
                h8 bb = *(const h8*)&Ks[16*nt + m][ks + 8*qd];
                sacc[nt] = mfma16(a, bb, sacc[nt]);
            }
        }
        // P = exp(S), C/D-layout -> LDS (A-layout for PV)
        #pragma unroll
        for (int nt = 0; nt < 4; ++nt)
            #pragma unroll
            for (int r = 0; r < 4; ++r)
                Ps[16*wv + 4*qd + r][16*nt + m] = (_Float16)__expf(sacc[nt][r]);
        __syncthreads();

        // row sums of P (for softmax denominator)
        {
            const int row = t & 63, seg = t >> 6;
            h8 p0 = *(const h8*)&Ps[row][seg*16];
            h8 p1 = *(const h8*)&Ps[row][seg*16 + 8];
            float s = 0.f;
            #pragma unroll
            for (int i = 0; i < 8; ++i) s += (float)p0[i] + (float)p1[i];
            lsum[seg][row] = s;
        }
        // O += P·V
        #pragma unroll
        for (int ks = 0; ks < 64; ks += 32) {
            h8 a = *(const h8*)&Ps[16*wv + m][ks + 8*qd];
            #pragma unroll
            for (int nt = 0; nt < 4; ++nt) {
                h8 bb = *(const h8*)&Vts[16*nt + m][ks + 8*qd];
                oacc[nt] = mfma16(a, bb, oacc[nt]);
            }
        }
        __syncthreads();
        if (t < 64) lrun += lsum[0][t] + lsum[1][t] + lsum[2][t] + lsum[3][t];
    }
    if (t < 64) lfin[t] = lrun;
    __syncthreads();

    // write o_attn[b][l][h*64+e]
    _Float16* ob = oa + ((size_t)(b*LL + l0))*(HH*EE) + h*EE;
    #pragma unroll
    for (int nt = 0; nt < 4; ++nt)
        #pragma unroll
        for (int r = 0; r < 4; ++r) {
            int row = 16*wv + 4*qd + r;
            ob[(size_t)row*(HH*EE) + 16*nt + m] = (_Float16)(oacc[nt][r] / lfin[row]);
        }
}

// ---------------- K4: output projection + bias ----------------
__global__ __launch_bounds__(256) void k_oproj(
    const _Float16* __restrict__ oa, const float* __restrict__ Wo,
    const float* __restrict__ bo, float* __restrict__ out)
{
    const int r0 = blockIdx.x * 64;   // row in [0, B*L)
    const int d0 = blockIdx.y * 64;   // output col
    __shared__ _Float16 As[64][72];
    __shared__ _Float16 Bs[64][72];
    const int t = threadIdx.x;
    const int wv = t >> 6, lane = t & 63;
    const int m = lane & 15, qd = lane >> 4;
    const int lrow = t >> 2, lc0 = (t & 3) * 16;

    f4 acc[4] = {};
    for (int kk = 0; kk < DD; kk += 64) {
        {   // A: o_attn natural [row][i]
            const _Float16* s = oa + (size_t)(r0 + lrow)*DD + kk + lc0;
            *(h8*)&As[lrow][lc0]     = *(const h8*)s;
            *(h8*)&As[lrow][lc0 + 8] = *(const h8*)(s + 8);
        }
        {   // B: Wo[d][i] natural == [n][k]
            const float* s = Wo + (size_t)(d0 + lrow)*DD + kk + lc0;
            #pragma unroll
            for (int i = 0; i < 16; i += 4) {
                f4 v4 = *(const f4*)(s + i);
                #pragma unroll
                for (int j = 0; j < 4; ++j) Bs[lrow][lc0 + i + j] = (_Float16)v4[j];
            }
        }
        __syncthreads();
        #pragma unroll
        for (int ks = 0; ks < 64; ks += 32) {
            h8 a = *(const h8*)&As[16*wv + m][ks + 8*qd];
            #pragma unroll
            for (int nt = 0; nt < 4; ++nt) {
                h8 bb = *(const h8*)&Bs[16*nt + m][ks + 8*qd];
                acc[nt] = mfma16(a, bb, acc[nt]);
            }
        }
        __syncthreads();
    }
    #pragma unroll
    for (int nt = 0; nt < 4; ++nt)
        #pragma unroll
        for (int r = 0; r < 4; ++r) {
            int row = 16*wv + 4*qd + r;
            int col = 16*nt + m;
            out[(size_t)(r0 + row)*DD + d0 + col] = acc[nt][r] + bo[d0 + col];
        }
}

extern "C" void kernel_launch(void* const* d_in, const int* in_sizes, int n_in,
                              void* d_out, int out_size, void* d_ws, size_t ws_size,
                              hipStream_t stream)
{
    const float* x  = (const float*)d_in[0];
    const int*   pm = (const int*)d_in[1];
    const float* Wq = (const float*)d_in[2];
    const float* Wk = (const float*)d_in[3];
    const float* Wv = (const float*)d_in[4];
    const float* Wo = (const float*)d_in[5];
    const float* bo = (const float*)d_in[6];
    float* out = (float*)d_out;

    const size_t QS = (size_t)16 * HH * LL * EE;   // 8388608 elems per tensor
    _Float16* q   = (_Float16*)d_ws;
    _Float16* k   = q + QS;
    _Float16* v   = k + QS;
    _Float16* oaw = v + QS;

    k_qkv0 <<<dim3(LL/64, 16, 17),    256, 0, stream>>>(x, Wq, Wk, Wv, q, k, v);
    k_qshuf<<<dim3(LL/64, 16, 7),     256, 0, stream>>>(x, pm, Wq, q);
    k_attn <<<dim3(LL/64, 16*HH),     256, 0, stream>>>(q, k, v, oaw);
    k_oproj<<<dim3(16*LL/64, DD/64),  256, 0, stream>>>(oaw, Wo, bo, out);
}

// Round 2
// 362.829 us; speedup vs baseline: 3.2145x; 3.2145x over previous
//
#include <hip/hip_runtime.h>

#define LL 1024
#define DD 512
#define HH 8
#define EE 64
#define LDX (LL*DD)
#define BB 16

typedef _Float16 h8 __attribute__((ext_vector_type(8)));
typedef float f4 __attribute__((ext_vector_type(4)));
typedef int i4 __attribute__((ext_vector_type(4)));

__device__ __forceinline__ f4 mfma16(h8 a, h8 b, f4 c) {
    return __builtin_amdgcn_mfma_f32_16x16x32_f16(a, b, c, 0, 0, 0);
}

// ---------------- K0: transpose x[b][s] -> xT16[s][b] (f16) ----------------
// One 32B row of xT16 holds all 16 batches for one source position s.
__global__ __launch_bounds__(256) void k_xt(
    const float* __restrict__ x, _Float16* __restrict__ xT)
{
    const int s = blockIdx.x * 256 + threadIdx.x;   // 0..524287
    h8 lo, hi;
    #pragma unroll
    for (int b = 0; b < 8; ++b)  lo[b] = (_Float16)x[(size_t)b*LDX + s];
    #pragma unroll
    for (int b = 0; b < 8; ++b)  hi[b] = (_Float16)x[(size_t)(b+8)*LDX + s];
    _Float16* d = xT + (size_t)s * BB;
    *(h8*)d       = lo;
    *(h8*)(d + 8) = hi;
}

// ---------------- K1: K/V all heads + Q head 0 ----------------
__global__ __launch_bounds__(256) void k_qkv0(
    const float* __restrict__ x, const float* __restrict__ Wq,
    const float* __restrict__ Wk, const float* __restrict__ Wv,
    _Float16* __restrict__ qw, _Float16* __restrict__ kw, _Float16* __restrict__ vw)
{
    const int l0 = blockIdx.x * 64;
    const int b  = blockIdx.y;
    const int z  = blockIdx.z;            // 0..7 K, 8..15 V, 16 Q(head0)
    const float* W; _Float16* out; int h; float mul = 1.f;
    if (z < 8)       { h = z;     W = Wk + (size_t)h*DD*EE; out = kw; }
    else if (z < 16) { h = z - 8; W = Wv + (size_t)h*DD*EE; out = vw; }
    else             { h = 0;     W = Wq;                   out = qw; mul = 0.125f; }
    out += ((size_t)(b*HH + h)*LL + l0) * EE;

    __shared__ _Float16 As[64][72];
    __shared__ _Float16 Bs[64][72];

    const int t = threadIdx.x;
    const int wv = t >> 6, lane = t & 63;
    const int m = lane & 15, qd = lane >> 4;
    const int lrow = t >> 2, lc0 = (t & 3) * 16;
    const float* xrow = x + (size_t)b*LDX + (size_t)(l0 + lrow)*DD;

    f4 acc[4] = {};

    for (int kk = 0; kk < DD; kk += 64) {
        #pragma unroll
        for (int i = 0; i < 16; i += 4) {
            f4 v4 = *(const f4*)(xrow + kk + lc0 + i);
            #pragma unroll
            for (int j = 0; j < 4; ++j) As[lrow][lc0 + i + j] = (_Float16)v4[j];
        }
        {
            const int e = t & 63, dd0 = t >> 6;
            #pragma unroll
            for (int d = 0; d < 64; d += 4)
                Bs[e][d + dd0] = (_Float16)W[(size_t)(kk + d + dd0)*EE + e];
        }
        __syncthreads();
        #pragma unroll
        for (int ks = 0; ks < 64; ks += 32) {
            h8 a = *(const h8*)&As[16*wv + m][ks + 8*qd];
            #pragma unroll
            for (int nt = 0; nt < 4; ++nt) {
                h8 bb = *(const h8*)&Bs[16*nt + m][ks + 8*qd];
                acc[nt] = mfma16(a, bb, acc[nt]);
            }
        }
        __syncthreads();
    }
    #pragma unroll
    for (int nt = 0; nt < 4; ++nt)
        #pragma unroll
        for (int r = 0; r < 4; ++r) {
            int row = 16*wv + 4*qd + r;
            out[(size_t)row*EE + 16*nt + m] = (_Float16)(acc[nt][r] * mul);
        }
}

// ---------------- K2: Q heads 1..7, gather via xT16 (batch-shared lines) ----
// Block = (h, 4 l-rows) x all 16 batches. M-row = l_local*16 + b.
// Per gather line xT16[p][0..15] all 16 batches are consumed at once.
__global__ __launch_bounds__(256) void k_qshuf(
    const _Float16* __restrict__ xT, const int* __restrict__ perms,
    const float* __restrict__ Wq, _Float16* __restrict__ qw)
{
    const int l0 = blockIdx.x * 4;        // 4 l-rows per block
    const int h  = blockIdx.y + 1;
    const float* W = Wq + (size_t)h*DD*EE;
    const int* pbase = perms + (size_t)(h-1)*LDX;

    __shared__ _Float16 As[64][72];
    __shared__ _Float16 Bs[64][72];

    const int t = threadIdx.x;
    const int wv = t >> 6, lane = t & 63;
    const int m = lane & 15, qd = lane >> 4;
    const int row  = t >> 2;              // 0..63 = l_local*16 + b
    const int llo  = row >> 4;            // == wv
    const int bidx = row & 15;
    const int c0   = (t & 3) * 16;

    f4 acc[4] = {};

    for (int kk = 0; kk < DD; kk += 64) {
        const int* ps = pbase + (size_t)(l0 + llo)*DD + kk + c0;
        h8 g0, g1;
        {
            i4 p0 = *(const i4*)(ps);
            i4 p1 = *(const i4*)(ps + 4);
            i4 p2 = *(const i4*)(ps + 8);
            i4 p3 = *(const i4*)(ps + 12);
            #pragma unroll
            for (int j = 0; j < 4; ++j) g0[j]     = xT[(size_t)p0[j]*BB + bidx];
            #pragma unroll
            for (int j = 0; j < 4; ++j) g0[4 + j] = xT[(size_t)p1[j]*BB + bidx];
            #pragma unroll
            for (int j = 0; j < 4; ++j) g1[j]     = xT[(size_t)p2[j]*BB + bidx];
            #pragma unroll
            for (int j = 0; j < 4; ++j) g1[4 + j] = xT[(size_t)p3[j]*BB + bidx];
        }
        *(h8*)&As[row][c0]     = g0;
        *(h8*)&As[row][c0 + 8] = g1;
        {
            const int e = t & 63, dd0 = t >> 6;
            #pragma unroll
            for (int d = 0; d < 64; d += 4)
                Bs[e][d + dd0] = (_Float16)W[(size_t)(kk + d + dd0)*EE + e];
        }
        __syncthreads();
        #pragma unroll
        for (int ks = 0; ks < 64; ks += 32) {
            h8 a = *(const h8*)&As[16*wv + m][ks + 8*qd];
            #pragma unroll
            for (int nt = 0; nt < 4; ++nt) {
                h8 bb = *(const h8*)&Bs[16*nt + m][ks + 8*qd];
                acc[nt] = mfma16(a, bb, acc[nt]);
            }
        }
        __syncthreads();
    }
    // D row = 16*wv + 4*qd + r  ->  l = l0 + wv, b = 4*qd + r
    #pragma unroll
    for (int nt = 0; nt < 4; ++nt)
        #pragma unroll
        for (int r = 0; r < 4; ++r) {
            int b = 4*qd + r;
            qw[((size_t)(b*HH + h)*LL + l0 + wv)*EE + 16*nt + m] =
                (_Float16)(acc[nt][r] * 0.125f);
        }
}

// ---------------- K3: attention (no-max streaming softmax) ----------------
__global__ __launch_bounds__(256) void k_attn(
    const _Float16* __restrict__ qw, const _Float16* __restrict__ kw,
    const _Float16* __restrict__ vw, _Float16* __restrict__ oa)
{
    const int l0 = blockIdx.x * 64;
    const int bh = blockIdx.y;
    const int b = bh >> 3, h = bh & 7;
    const _Float16* qb = qw + ((size_t)bh*LL + l0)*EE;
    const _Float16* kb = kw + (size_t)bh*LL*EE;
    const _Float16* vb = vw + (size_t)bh*LL*EE;

    __shared__ _Float16 Qs[64][72], Ks[64][72], Vts[64][72], Ps[64][72];
    __shared__ float lsum[4][64];
    __shared__ float lfin[64];

    const int t = threadIdx.x;
    const int wv = t >> 6, lane = t & 63;
    const int m = lane & 15, qd = lane >> 4;
    const int lrow = t >> 2, lc0 = (t & 3) * 16;

    {
        const _Float16* s = qb + (size_t)lrow*EE + lc0;
        *(h8*)&Qs[lrow][lc0]     = *(const h8*)s;
        *(h8*)&Qs[lrow][lc0 + 8] = *(const h8*)(s + 8);
    }

    f4 oacc[4] = {};
    float lrun = 0.f;

    for (int kt = 0; kt < 16; ++kt) {
        {
            const _Float16* s = kb + (size_t)(kt*64 + lrow)*EE + lc0;
            *(h8*)&Ks[lrow][lc0]     = *(const h8*)s;
            *(h8*)&Ks[lrow][lc0 + 8] = *(const h8*)(s + 8);
            const _Float16* s2 = vb + (size_t)(kt*64 + lrow)*EE + lc0;
            h8 v0 = *(const h8*)s2;
            h8 v1 = *(const h8*)(s2 + 8);
            #pragma unroll
            for (int i = 0; i < 8; ++i) Vts[lc0 + i][lrow]     = v0[i];
            #pragma unroll
            for (int i = 0; i < 8; ++i) Vts[lc0 + 8 + i][lrow] = v1[i];
        }
        __syncthreads();

        f4 sacc[4] = {};
        #pragma unroll
        for (int ks = 0; ks < 64; ks += 32) {
            h8 a = *(const h8*)&Qs[16*wv + m][ks + 8*qd];
            #pragma unroll
            for (int nt = 0; nt < 4; ++nt) {
                h8 bb = *(const h8*)&Ks[16*nt + m][ks + 8*qd];
                sacc[nt] = mfma16(a, bb, sacc[nt]);
            }
        }
        #pragma unroll
        for (int nt = 0; nt < 4; ++nt)
            #pragma unroll
            for (int r = 0; r < 4; ++r)
                Ps[16*wv + 4*qd + r][16*nt + m] = (_Float16)__expf(sacc[nt][r]);
        __syncthreads();

        {
            const int rw = t & 63, seg = t >> 6;
            h8 p0 = *(const h8*)&Ps[rw][seg*16];
            h8 p1 = *(const h8*)&Ps[rw][seg*16 + 8];
            float s = 0.f;
            #pragma unroll
            for (int i = 0; i < 8; ++i) s += (float)p0[i] + (float)p1[i];
            lsum[seg][rw] = s;
        }
        #pragma unroll
        for (int ks = 0; ks < 64; ks += 32) {
            h8 a = *(const h8*)&Ps[16*wv + m][ks + 8*qd];
            #pragma unroll
            for (int nt = 0; nt < 4; ++nt) {
                h8 bb = *(const h8*)&Vts[16*nt + m][ks + 8*qd];
                oacc[nt] = mfma16(a, bb, oacc[nt]);
            }
        }
        __syncthreads();
        if (t < 64) lrun += lsum[0][t] + lsum[1][t] + lsum[2][t] + lsum[3][t];
    }
    if (t < 64) lfin[t] = lrun;
    __syncthreads();

    _Float16* ob = oa + ((size_t)(b*LL + l0))*(HH*EE) + h*EE;
    #pragma unroll
    for (int nt = 0; nt < 4; ++nt)
        #pragma unroll
        for (int r = 0; r < 4; ++r) {
            int row = 16*wv + 4*qd + r;
            ob[(size_t)row*(HH*EE) + 16*nt + m] = (_Float16)(oacc[nt][r] / lfin[row]);
        }
}

// ---------------- K4: output projection + bias ----------------
__global__ __launch_bounds__(256) void k_oproj(
    const _Float16* __restrict__ oa, const float* __restrict__ Wo,
    const float* __restrict__ bo, float* __restrict__ out)
{
    const int r0 = blockIdx.x * 64;
    const int d0 = blockIdx.y * 64;
    __shared__ _Float16 As[64][72];
    __shared__ _Float16 Bs[64][72];
    const int t = threadIdx.x;
    const int wv = t >> 6, lane = t & 63;
    const int m = lane & 15, qd = lane >> 4;
    const int lrow = t >> 2, lc0 = (t & 3) * 16;

    f4 acc[4] = {};
    for (int kk = 0; kk < DD; kk += 64) {
        {
            const _Float16* s = oa + (size_t)(r0 + lrow)*DD + kk + lc0;
            *(h8*)&As[lrow][lc0]     = *(const h8*)s;
            *(h8*)&As[lrow][lc0 + 8] = *(const h8*)(s + 8);
        }
        {
            const float* s = Wo + (size_t)(d0 + lrow)*DD + kk + lc0;
            #pragma unroll
            for (int i = 0; i < 16; i += 4) {
                f4 v4 = *(const f4*)(s + i);
                #pragma unroll
                for (int j = 0; j < 4; ++j) Bs[lrow][lc0 + i + j] = (_Float16)v4[j];
            }
        }
        __syncthreads();
        #pragma unroll
        for (int ks = 0; ks < 64; ks += 32) {
            h8 a = *(const h8*)&As[16*wv + m][ks + 8*qd];
            #pragma unroll
            for (int nt = 0; nt < 4; ++nt) {
                h8 bb = *(const h8*)&Bs[16*nt + m][ks + 8*qd];
                acc[nt] = mfma16(a, bb, acc[nt]);
            }
        }
        __syncthreads();
    }
    #pragma unroll
    for (int nt = 0; nt < 4; ++nt)
        #pragma unroll
        for (int r = 0; r < 4; ++r) {
            int row = 16*wv + 4*qd + r;
            int col = 16*nt + m;
            out[(size_t)(r0 + row)*DD + d0 + col] = acc[nt][r] + bo[d0 + col];
        }
}

extern "C" void kernel_launch(void* const* d_in, const int* in_sizes, int n_in,
                              void* d_out, int out_size, void* d_ws, size_t ws_size,
                              hipStream_t stream)
{
    const float* x  = (const float*)d_in[0];
    const int*   pm = (const int*)d_in[1];
    const float* Wq = (const float*)d_in[2];
    const float* Wk = (const float*)d_in[3];
    const float* Wv = (const float*)d_in[4];
    const float* Wo = (const float*)d_in[5];
    const float* bo = (const float*)d_in[6];
    float* out = (float*)d_out;

    const size_t QS = (size_t)BB * HH * LL * EE;   // 8388608 elems
    _Float16* q   = (_Float16*)d_ws;
    _Float16* k   = q + QS;
    _Float16* v   = k + QS;
    _Float16* oaw = v + QS;          // [B*L, H*E]
    _Float16* xT  = oaw;             // alias: xT dead before k_attn writes oaw

    k_xt   <<<dim3(LDX/256),          256, 0, stream>>>(x, xT);
    k_qkv0 <<<dim3(LL/64, BB, 17),    256, 0, stream>>>(x, Wq, Wk, Wv, q, k, v);
    k_qshuf<<<dim3(LL/4, HH-1),       256, 0, stream>>>(xT, pm, Wq, q);
    k_attn <<<dim3(LL/64, BB*HH),     256, 0, stream>>>(q, k, v, oaw);
    k_oproj<<<dim3(BB*LL/64, DD/64),  256, 0, stream>>>(oaw, Wo, bo, out);
}